// Round 2
// baseline (137.859 us; speedup 1.0000x reference)
//
#include <hip/hip_runtime.h>
#include <math.h>

typedef unsigned short u16;
typedef unsigned int u32;
typedef __bf16 bf16x8 __attribute__((ext_vector_type(8)));
typedef float f32x4 __attribute__((ext_vector_type(4)));

#define LOG2E 1.44269504088896f
#define SCALING 0.17677669529663687f   // 32^-0.5
#define LOG2_10000 13.287712379549449f

__device__ __forceinline__ float bf2f(u16 v) {
    u32 u = ((u32)v) << 16; float f; __builtin_memcpy(&f, &u, 4); return f;
}
__device__ __forceinline__ u16 f2bf(float f) {
    u32 u; __builtin_memcpy(&u, &f, 4);
    u = u + 0x7FFFu + ((u >> 16) & 1u);
    return (u16)(u >> 16);
}
__device__ __forceinline__ f32x4 mfma16(bf16x8 a, bf16x8 b, f32x4 c) {
    return __builtin_amdgcn_mfma_f32_16x16x32_bf16(a, b, c, 0, 0, 0);
}
__device__ __forceinline__ float decay_l2(int h) {
    // log(1 - 2^(-2 - 5h/8)) * log2(e)   (exp(x) == exp2(x*log2e))
    return logf(1.0f - exp2f(-2.0f - 0.625f * (float)h)) * LOG2E;
}

// ---------------- mask rowsum: rsq[h*1024+q] = 1/sqrt(sum_k exp(decay*d)) -----
__global__ __launch_bounds__(256) void mask_rsq_kernel(float* __restrict__ rsq) {
    int gw = (blockIdx.x * 256 + threadIdx.x) >> 6;   // wave id: 0..8191
    int lane = threadIdx.x & 63;
    int h = gw >> 10, q = gw & 1023;
    float dec = decay_l2(h);
    int q1 = q >> 5, q2 = q & 31;
    float s = 0.0f;
    for (int k = lane; k < 1024; k += 64) {
        int k1 = k >> 5, k2 = k & 31;
        float d = (float)(abs(q1 - k1) + abs(q2 - k2));
        s += exp2f(dec * d);
    }
#pragma unroll
    for (int m = 32; m; m >>= 1) s += __shfl_xor(s, m);
    if (lane == 0) rsq[gw] = rsqrtf(s);
}

// ---------------- mask table (bf16): mask[h][q][k] -----------------------------
__global__ __launch_bounds__(256) void mask_build_kernel(const float* __restrict__ rsq,
                                                         u16* __restrict__ mask) {
    int t = blockIdx.x * 256 + threadIdx.x;   // 1,048,576 threads
    int row = t >> 7;                          // (h,q) row: 0..8191
    int k0 = (t & 127) << 3;                   // 8 k's per thread
    int h = row >> 10, q = row & 1023;
    float dec = decay_l2(h);
    float r = rsq[row];
    int q1 = q >> 5, q2 = q & 31;
    int k1 = k0 >> 5, k2b = k0 & 31;           // k0 % 32 in {0,8,16,24}: same k1 for all 8
    union { int4 v; u16 s[8]; } tmp;
#pragma unroll
    for (int i = 0; i < 8; i++) {
        float d = (float)(abs(q1 - k1) + abs(q2 - (k2b + i)));
        tmp.s[i] = f2bf(exp2f(dec * d) * r);
    }
    *(int4*)&mask[(long)row * 1024 + k0] = tmp.v;
}

// ---------------- GEMM C[i][e] = sum_j A[i][j] W[e][j] ------------------------
// A is f32 (AF32=1) or bf16 (AF32=0). W always f32. Outputs:
// modes 0=q (theta-shift, bf16 qkv layout), 1=k (scale+shift), 2=v, 3=plain f32 out
template<int AF32>
__global__ __launch_bounds__(256) void gemm_bt_kernel(
    const void* __restrict__ Av,
    const float* __restrict__ W0, const float* __restrict__ W1, const float* __restrict__ W2,
    u16* __restrict__ O0, u16* __restrict__ O1, u16* __restrict__ O2,
    float* __restrict__ Of, int mode_base) {
    __shared__ u16 As[64 * 136];   // 64 rows x 128 K-chunk, pad to 136 (272B, 16B-aligned)
    __shared__ u16 Ws[64 * 136];
    int z = blockIdx.z;
    const float* W = (z == 0) ? W0 : (z == 1) ? W1 : W2;
    u16* O = (z == 0) ? O0 : (z == 1) ? O1 : O2;
    int mode = mode_base + z;
    int r0 = blockIdx.x * 64, n0 = blockIdx.y * 64;
    int tid = threadIdx.x;
    int w = tid >> 6, lane = tid & 63, ln = lane & 15, quad = lane >> 4;
    f32x4 acc[4] = {};
#pragma unroll
    for (int ch = 0; ch < 2; ch++) {
        int k0 = ch * 128;
        if (ch) __syncthreads();
        // stage W (f32 -> bf16)
#pragma unroll
        for (int i = 0; i < 8; i++) {
            int c = tid + i * 256;
            int row = c >> 5, seg = c & 31;   // 4 floats per thread-slot
            float4 wv = *(const float4*)&W[(long)(n0 + row) * 256 + k0 + seg * 4];
            union { int2 v; u16 s[4]; } t;
            t.s[0] = f2bf(wv.x); t.s[1] = f2bf(wv.y); t.s[2] = f2bf(wv.z); t.s[3] = f2bf(wv.w);
            *(int2*)&Ws[row * 136 + seg * 4] = t.v;
        }
        // stage A
        if (AF32) {
            const float* A = (const float*)Av;
#pragma unroll
            for (int i = 0; i < 8; i++) {
                int c = tid + i * 256;
                int row = c >> 5, seg = c & 31;
                float4 av = *(const float4*)&A[(long)(r0 + row) * 256 + k0 + seg * 4];
                union { int2 v; u16 s[4]; } t;
                t.s[0] = f2bf(av.x); t.s[1] = f2bf(av.y); t.s[2] = f2bf(av.z); t.s[3] = f2bf(av.w);
                *(int2*)&As[row * 136 + seg * 4] = t.v;
            }
        } else {
            const u16* A = (const u16*)Av;
#pragma unroll
            for (int i = 0; i < 4; i++) {
                int c = tid + i * 256;
                int row = c >> 4, seg = c & 15;   // 8 u16 per thread-slot
                *(int4*)&As[row * 136 + seg * 8] = *(const int4*)&A[(long)(r0 + row) * 256 + k0 + seg * 8];
            }
        }
        __syncthreads();
#pragma unroll
        for (int kt = 0; kt < 4; kt++) {
            bf16x8 a = *(const bf16x8*)&As[(w * 16 + ln) * 136 + kt * 32 + quad * 8];
#pragma unroll
            for (int nt = 0; nt < 4; nt++) {
                bf16x8 b = *(const bf16x8*)&Ws[(nt * 16 + ln) * 136 + kt * 32 + quad * 8];
                acc[nt] = mfma16(a, b, acc[nt]);
            }
        }
    }
    int rowg = r0 + w * 16 + quad * 4;   // C row = quad*4 + reg
    if (mode == 3) {
#pragma unroll
        for (int nt = 0; nt < 4; nt++) {
            int e = n0 + nt * 16 + ln;
#pragma unroll
            for (int r = 0; r < 4; r++)
                Of[(long)(rowg + r) * 256 + e] = acc[nt][r];
        }
        return;
    }
    float scl = (mode == 1) ? SCALING : 1.0f;
#pragma unroll
    for (int nt = 0; nt < 4; nt++) {
        int e = n0 + nt * 16 + ln;
        int d = e & 31, hh = e >> 5;
        float ang = exp2f(-LOG2_10000 * (1.0f / 15.0f) * (float)(d >> 1));
#pragma unroll
        for (int r = 0; r < 4; r++) {
            int gi = rowg + r;
            int b = gi >> 10, l = gi & 1023;
            float v = acc[nt][r] * scl;
            float p = __shfl_xor(v, 1);   // partner col e^1, same row (uniform exec)
            float res;
            if (mode == 2) {
                res = v;
            } else {
                float idx = (float)((l >> 5) + (l & 31));
                float sv, cv;
                __sincosf(idx * ang, &sv, &cv);
                res = (d & 1) ? (v * cv + p * sv) : (v * cv - p * sv);
            }
            O[(((long)(b * 8 + hh)) * 1024 + l) * 32 + d] = f2bf(res);
        }
    }
}

// ---------------- fused retention + LN + GELU ---------------------------------
__global__ __launch_bounds__(256) void attn_kernel(
    const u16* __restrict__ qr, const u16* __restrict__ kr, const u16* __restrict__ vr,
    const u16* __restrict__ mask, const float* __restrict__ lng, const float* __restrict__ lnb,
    u16* __restrict__ out) {
    __shared__ u16 Qs[64 * 40];   // 64 q-rows x 32, pad 40 (80B stride, 16B-aligned)
    __shared__ u16 Ks[64 * 40];
    __shared__ u16 Vt[32 * 72];   // V transposed: [d][kk], pad 72 (144B)
    __shared__ u16 Ps[64 * 72];   // P tile for C->A layout round-trip
    int b = blockIdx.z, h = blockIdx.y, q0 = blockIdx.x * 64;
    int tid = threadIdx.x, w = tid >> 6, lane = tid & 63, ln = lane & 15, quad = lane >> 4;
    long bh = b * 8 + h;
    const u16* qb = qr + bh * 32768;
    const u16* kb = kr + bh * 32768;
    const u16* vb = vr + bh * 32768;
    const u16* mb = mask + (long)h * 1048576;
    {
        int row = tid >> 2, seg = tid & 3;
        *(int4*)&Qs[row * 40 + seg * 8] = *(const int4*)&qb[(q0 + row) * 32 + seg * 8];
    }
    __syncthreads();
    int m0 = w * 16;
    bf16x8 aq = *(const bf16x8*)&Qs[(m0 + ln) * 40 + quad * 8];   // A[m=ln][k=quad*8+j]
    f32x4 accO[2] = {};
    float den[4] = {0.f, 0.f, 0.f, 0.f};
    for (int kt = 0; kt < 16; kt++) {
        int k0 = kt * 64;
        {   // stage K tile + V tile (transposed)
            int row = tid >> 2, seg = tid & 3;
            *(int4*)&Ks[row * 40 + seg * 8] = *(const int4*)&kb[(k0 + row) * 32 + seg * 8];
            union { int4 v; u16 s[8]; } vv;
            vv.v = *(const int4*)&vb[(k0 + row) * 32 + seg * 8];
#pragma unroll
            for (int i = 0; i < 8; i++) Vt[(seg * 8 + i) * 72 + row] = vv.s[i];
        }
        __syncthreads();
        f32x4 zero = {};
#pragma unroll
        for (int nt = 0; nt < 4; nt++) {
            bf16x8 bk = *(const bf16x8*)&Ks[(nt * 16 + ln) * 40 + quad * 8];
            f32x4 s = mfma16(aq, bk, zero);   // rows m0+quad*4+r, col nt*16+ln
            int col = nt * 16 + ln;
            const u16* mrow = mb + (long)(q0 + m0 + quad * 4) * 1024 + k0 + col;
#pragma unroll
            for (int r = 0; r < 4; r++) {
                float p = s[r] * bf2f(mrow[(long)r * 1024]);
                den[r] += fabsf(p);
                Ps[(m0 + quad * 4 + r) * 72 + col] = f2bf(p);   // wave-private rows
            }
        }
        // PV: wave-local LDS RAW on Ps (compiler inserts lgkmcnt waits)
#pragma unroll
        for (int c2 = 0; c2 < 2; c2++) {
            bf16x8 ap = *(const bf16x8*)&Ps[(m0 + ln) * 72 + c2 * 32 + quad * 8];
#pragma unroll
            for (int nv = 0; nv < 2; nv++) {
                bf16x8 bv = *(const bf16x8*)&Vt[(nv * 16 + ln) * 72 + c2 * 32 + quad * 8];
                accO[nv] = mfma16(ap, bv, accO[nv]);
            }
        }
        __syncthreads();   // protect Ks/Vt restage next iter
    }
    // reduce den across the 16 lanes sharing rows quad*4+r
#pragma unroll
    for (int m = 1; m < 16; m <<= 1)
#pragma unroll
        for (int r = 0; r < 4; r++) den[r] += __shfl_xor(den[r], m);
    float o[2][4], s1[4], s2[4];
#pragma unroll
    for (int r = 0; r < 4; r++) {
        float id = 1.0f / fminf(fmaxf(den[r], 1.0f), 50000.0f);
        o[0][r] = accO[0][r] * id;
        o[1][r] = accO[1][r] * id;
        s1[r] = o[0][r] + o[1][r];
        s2[r] = o[0][r] * o[0][r] + o[1][r] * o[1][r];
    }
#pragma unroll
    for (int m = 1; m < 16; m <<= 1)
#pragma unroll
        for (int r = 0; r < 4; r++) {
            s1[r] += __shfl_xor(s1[r], m);
            s2[r] += __shfl_xor(s2[r], m);
        }
    float g[2] = {lng[ln], lng[16 + ln]};
    float bb[2] = {lnb[ln], lnb[16 + ln]};
#pragma unroll
    for (int r = 0; r < 4; r++) {
        float mean = s1[r] * (1.0f / 32.0f);
        float var = s2[r] * (1.0f / 32.0f) - mean * mean;
        float rstd = rsqrtf(var + 1e-5f);
        int l = q0 + m0 + quad * 4 + r;
#pragma unroll
        for (int nv = 0; nv < 2; nv++) {
            float x = (o[nv][r] - mean) * rstd * g[nv] + bb[nv];
            float ge = 0.5f * x * (1.0f + erff(x * 0.70710678118654752f));
            out[((long)(b * 1024 + l)) * 256 + h * 32 + nv * 16 + ln] = f2bf(ge);
        }
    }
}

extern "C" void kernel_launch(void* const* d_in, const int* in_sizes, int n_in,
                              void* d_out, int out_size, void* d_ws, size_t ws_size,
                              hipStream_t stream) {
    const float* x   = (const float*)d_in[0];
    const float* Wq  = (const float*)d_in[1];
    const float* Wk  = (const float*)d_in[2];
    const float* Wv  = (const float*)d_in[3];
    const float* Wo  = (const float*)d_in[4];
    const float* lng = (const float*)d_in[5];
    const float* lnb = (const float*)d_in[6];
    float* outp = (float*)d_out;

    // workspace layout (~32 MB)
    u16* qr    = (u16*)d_ws;            // [B][H][L][32] bf16
    u16* kr    = qr + 2097152;
    u16* vr    = kr + 2097152;
    u16* attn  = vr + 2097152;          // [B*L][256] bf16
    u16* maskb = attn + 2097152;        // [H][L][L] bf16 (16 MB)
    float* rsq = (float*)(maskb + 8388608);   // [H][L] f32

    mask_rsq_kernel<<<2048, 256, 0, stream>>>(rsq);
    mask_build_kernel<<<4096, 256, 0, stream>>>(rsq, maskb);
    gemm_bt_kernel<1><<<dim3(128, 4, 3), 256, 0, stream>>>(x, Wq, Wk, Wv, qr, kr, vr, nullptr, 0);
    attn_kernel<<<dim3(16, 8, 8), 256, 0, stream>>>(qr, kr, vr, maskb, lng, lnb, attn);
    gemm_bt_kernel<0><<<dim3(128, 4, 1), 256, 0, stream>>>(attn, Wo, Wo, Wo, nullptr, nullptr, nullptr, outp, 3);
}

// Round 3
// 128.930 us; speedup vs baseline: 1.0693x; 1.0693x over previous
//
#include <hip/hip_runtime.h>
#include <math.h>

typedef unsigned short u16;
typedef unsigned int u32;
typedef __bf16 bf16x8 __attribute__((ext_vector_type(8)));
typedef float f32x4 __attribute__((ext_vector_type(4)));

#define SCALING 0.17677669529663687f   // 32^-0.5
#define LOG2E 1.44269504088896f
#define LOG2_10000 13.287712379549449f

__device__ __forceinline__ u16 f2bf(float f) {
    u32 u; __builtin_memcpy(&u, &f, 4);
    u = u + 0x7FFFu + ((u >> 16) & 1u);
    return (u16)(u >> 16);
}
__device__ __forceinline__ f32x4 mfma16(bf16x8 a, bf16x8 b, f32x4 c) {
    return __builtin_amdgcn_mfma_f32_16x16x32_bf16(a, b, c, 0, 0, 0);
}
__device__ __forceinline__ float decay_l2(int h) {
    // log(1 - 2^(-2 - 5h/8)) * log2(e)  (so exp2(dec*d) == exp(decay*d))
    return logf(1.0f - exp2f(-2.0f - 0.625f * (float)h)) * LOG2E;
}

// ---------------- f32 -> bf16 pre-convert: x (1024 blocks) + 4 weights (32 each)
__global__ __launch_bounds__(256) void cvt_kernel(
    const float* __restrict__ x,
    const float* __restrict__ Wq, const float* __restrict__ Wk,
    const float* __restrict__ Wv, const float* __restrict__ Wo,
    u16* __restrict__ xb, u16* __restrict__ wb) {
    int bid = blockIdx.x;
    const float* src; u16* dst; int off;
    if (bid < 1024) { src = x; dst = xb; off = bid * 2048; }
    else {
        int wsel = (bid - 1024) >> 5;
        src = (wsel == 0) ? Wq : (wsel == 1) ? Wk : (wsel == 2) ? Wv : Wo;
        dst = wb + wsel * 65536;
        off = ((bid - 1024) & 31) * 2048;
    }
    int i = off + threadIdx.x * 8;
    float4 a = *(const float4*)&src[i];
    float4 b = *(const float4*)&src[i + 4];
    union { int4 v; u16 s[8]; } t;
    t.s[0] = f2bf(a.x); t.s[1] = f2bf(a.y); t.s[2] = f2bf(a.z); t.s[3] = f2bf(a.w);
    t.s[4] = f2bf(b.x); t.s[5] = f2bf(b.y); t.s[6] = f2bf(b.z); t.s[7] = f2bf(b.w);
    *(int4*)&dst[i] = t.v;
}

// ---------------- GEMM C[i][e] = sum_j A[i][j] W[e][j]  (all bf16 in) ---------
// modes: 0=q (theta-shift, qkv layout), 1=k (scale+shift), 2=v, 3=plain f32 out
__global__ __launch_bounds__(256) void gemm_bt_kernel(
    const u16* __restrict__ A, const u16* __restrict__ Wb,
    u16* __restrict__ O0, u16* __restrict__ O1, u16* __restrict__ O2,
    float* __restrict__ Of, int mode_base) {
    __shared__ u16 As[64 * 136];   // 64 rows x 128 K-chunk, pad 136 (16B-aligned)
    __shared__ u16 Ws[64 * 136];
    int z = blockIdx.z;
    const u16* W = Wb + z * 65536;
    u16* O = (z == 0) ? O0 : (z == 1) ? O1 : O2;
    int mode = mode_base + z;
    int n0 = blockIdx.x * 64, r0 = blockIdx.y * 64;   // n fast => A row-block L2 reuse
    int tid = threadIdx.x;
    int w = tid >> 6, lane = tid & 63, ln = lane & 15, quad = lane >> 4;
    f32x4 acc[4] = {};
#pragma unroll
    for (int ch = 0; ch < 2; ch++) {
        int k0 = ch * 128;
        if (ch) __syncthreads();
#pragma unroll
        for (int i = 0; i < 4; i++) {
            int c = tid + i * 256;
            int row = c >> 4, seg = c & 15;
            *(int4*)&As[row * 136 + seg * 8] = *(const int4*)&A[(long)(r0 + row) * 256 + k0 + seg * 8];
            *(int4*)&Ws[row * 136 + seg * 8] = *(const int4*)&W[(long)(n0 + row) * 256 + k0 + seg * 8];
        }
        __syncthreads();
#pragma unroll
        for (int kt = 0; kt < 4; kt++) {
            bf16x8 a = *(const bf16x8*)&As[(w * 16 + ln) * 136 + kt * 32 + quad * 8];
#pragma unroll
            for (int nt = 0; nt < 4; nt++) {
                bf16x8 b = *(const bf16x8*)&Ws[(nt * 16 + ln) * 136 + kt * 32 + quad * 8];
                acc[nt] = mfma16(a, b, acc[nt]);
            }
        }
    }
    int rowg = r0 + w * 16 + quad * 4;   // C row = quad*4 + reg
    if (mode == 3) {
#pragma unroll
        for (int nt = 0; nt < 4; nt++) {
            int e = n0 + nt * 16 + ln;
#pragma unroll
            for (int r = 0; r < 4; r++)
                Of[(long)(rowg + r) * 256 + e] = acc[nt][r];
        }
        return;
    }
    float scl = (mode == 1) ? SCALING : 1.0f;
#pragma unroll
    for (int nt = 0; nt < 4; nt++) {
        int e = n0 + nt * 16 + ln;
        int d = e & 31, hh = e >> 5;
        float ang = exp2f(-LOG2_10000 * (1.0f / 15.0f) * (float)(d >> 1));
#pragma unroll
        for (int r = 0; r < 4; r++) {
            int gi = rowg + r;
            int b = gi >> 10, l = gi & 1023;
            float v = acc[nt][r] * scl;
            float p = __shfl_xor(v, 1);   // partner col e^1, same row (uniform exec)
            float res;
            if (mode == 2) {
                res = v;
            } else {
                float idx = (float)((l >> 5) + (l & 31));
                float sv, cv;
                __sincosf(idx * ang, &sv, &cv);
                res = (d & 1) ? (v * cv + p * sv) : (v * cv - p * sv);
            }
            O[(((long)(b * 8 + hh)) * 1024 + l) * 32 + d] = f2bf(res);
        }
    }
}

// ---------------- fused retention + LN + GELU (mask computed in-kernel) -------
__global__ __launch_bounds__(256) void attn_kernel(
    const u16* __restrict__ qr, const u16* __restrict__ kr, const u16* __restrict__ vr,
    const float* __restrict__ lng, const float* __restrict__ lnb,
    u16* __restrict__ out) {
    __shared__ u16 Qs[64 * 40];   // 64 q-rows x 32, pad 40
    __shared__ u16 Ks[64 * 40];
    __shared__ u16 Vt[32 * 72];   // V transposed [d][kk], pad 72
    __shared__ u16 Ps[64 * 72];   // P tile C->A layout round-trip
    __shared__ float Tt[64];      // exp2(dec*d), d=0..62
    __shared__ float Ss[32];      // 1D rowsum factor
    __shared__ float rq[64];      // rsqrt(rowsum) for q0..q0+63
    int b = blockIdx.z, h = blockIdx.y, q0 = blockIdx.x * 64;
    int tid = threadIdx.x, w = tid >> 6, lane = tid & 63, ln = lane & 15, quad = lane >> 4;
    long bh = b * 8 + h;
    const u16* qb = qr + bh * 32768;
    const u16* kb = kr + bh * 32768;
    const u16* vb = vr + bh * 32768;
    float dec = decay_l2(h);
    {
        int row = tid >> 2, seg = tid & 3;
        *(int4*)&Qs[row * 40 + seg * 8] = *(const int4*)&qb[(q0 + row) * 32 + seg * 8];
        if (tid < 63) Tt[tid] = exp2f(dec * (float)tid);
    }
    __syncthreads();
    if (tid < 32) {
        float s = 0.0f;
#pragma unroll
        for (int b2 = 0; b2 < 32; b2++) s += Tt[abs(tid - b2)];
        Ss[tid] = s;
    }
    __syncthreads();
    if (tid < 64) {
        int q = q0 + tid;
        rq[tid] = rsqrtf(Ss[q >> 5] * Ss[q & 31]);
    }
    __syncthreads();
    int m0 = w * 16;
    bf16x8 aq = *(const bf16x8*)&Qs[(m0 + ln) * 40 + quad * 8];   // A[m=ln][k=quad*8+j]
    int q1r[4], q2r[4]; float rqv[4];
#pragma unroll
    for (int r = 0; r < 4; r++) {
        int qrow = m0 + quad * 4 + r;
        int q = q0 + qrow;
        q1r[r] = q >> 5; q2r[r] = q & 31;
        rqv[r] = rq[qrow];
    }
    f32x4 accO[2] = {};
    float den[4] = {0.f, 0.f, 0.f, 0.f};
    for (int kt = 0; kt < 16; kt++) {
        int k0 = kt * 64;
        {   // stage K tile + V tile (transposed)
            int row = tid >> 2, seg = tid & 3;
            *(int4*)&Ks[row * 40 + seg * 8] = *(const int4*)&kb[(k0 + row) * 32 + seg * 8];
            union { int4 v; u16 s[8]; } vv;
            vv.v = *(const int4*)&vb[(k0 + row) * 32 + seg * 8];
#pragma unroll
            for (int i = 0; i < 8; i++) Vt[(seg * 8 + i) * 72 + row] = vv.s[i];
        }
        __syncthreads();
        f32x4 zero = {};
#pragma unroll
        for (int nt = 0; nt < 4; nt++) {
            bf16x8 bk = *(const bf16x8*)&Ks[(nt * 16 + ln) * 40 + quad * 8];
            f32x4 s = mfma16(aq, bk, zero);   // rows m0+quad*4+r, col nt*16+ln
            int col = nt * 16 + ln;
            int k = k0 + col, k1 = k >> 5, k2 = k & 31;
#pragma unroll
            for (int r = 0; r < 4; r++) {
                int d = abs(q1r[r] - k1) + abs(q2r[r] - k2);
                float m = Tt[d] * rqv[r];
                float p = s[r] * m;
                den[r] += fabsf(p);
                Ps[(m0 + quad * 4 + r) * 72 + col] = f2bf(p);   // wave-private rows
            }
        }
        // PV: wave-local LDS RAW on Ps (compiler inserts lgkmcnt waits)
#pragma unroll
        for (int c2 = 0; c2 < 2; c2++) {
            bf16x8 ap = *(const bf16x8*)&Ps[(m0 + ln) * 72 + c2 * 32 + quad * 8];
#pragma unroll
            for (int nv = 0; nv < 2; nv++) {
                bf16x8 bv = *(const bf16x8*)&Vt[(nv * 16 + ln) * 72 + c2 * 32 + quad * 8];
                accO[nv] = mfma16(ap, bv, accO[nv]);
            }
        }
        __syncthreads();   // protect Ks/Vt restage next iter
    }
    // reduce den across the 16 lanes sharing rows quad*4+r
#pragma unroll
    for (int m = 1; m < 16; m <<= 1)
#pragma unroll
        for (int r = 0; r < 4; r++) den[r] += __shfl_xor(den[r], m);
    float o[2][4], s1[4], s2[4];
#pragma unroll
    for (int r = 0; r < 4; r++) {
        float id = 1.0f / fminf(fmaxf(den[r], 1.0f), 50000.0f);
        o[0][r] = accO[0][r] * id;
        o[1][r] = accO[1][r] * id;
        s1[r] = o[0][r] + o[1][r];
        s2[r] = o[0][r] * o[0][r] + o[1][r] * o[1][r];
    }
#pragma unroll
    for (int m = 1; m < 16; m <<= 1)
#pragma unroll
        for (int r = 0; r < 4; r++) {
            s1[r] += __shfl_xor(s1[r], m);
            s2[r] += __shfl_xor(s2[r], m);
        }
    float g[2] = {lng[ln], lng[16 + ln]};
    float bb[2] = {lnb[ln], lnb[16 + ln]};
#pragma unroll
    for (int r = 0; r < 4; r++) {
        float mean = s1[r] * (1.0f / 32.0f);
        float var = s2[r] * (1.0f / 32.0f) - mean * mean;
        float rstd = rsqrtf(var + 1e-5f);
        int l = q0 + m0 + quad * 4 + r;
#pragma unroll
        for (int nv = 0; nv < 2; nv++) {
            float x = (o[nv][r] - mean) * rstd * g[nv] + bb[nv];
            float ge = 0.5f * x * (1.0f + erff(x * 0.70710678118654752f));
            out[((long)(b * 1024 + l)) * 256 + h * 32 + nv * 16 + ln] = f2bf(ge);
        }
    }
}

extern "C" void kernel_launch(void* const* d_in, const int* in_sizes, int n_in,
                              void* d_out, int out_size, void* d_ws, size_t ws_size,
                              hipStream_t stream) {
    const float* x   = (const float*)d_in[0];
    const float* Wq  = (const float*)d_in[1];
    const float* Wk  = (const float*)d_in[2];
    const float* Wv  = (const float*)d_in[3];
    const float* Wo  = (const float*)d_in[4];
    const float* lng = (const float*)d_in[5];
    const float* lnb = (const float*)d_in[6];
    float* outp = (float*)d_out;

    // workspace (~21.5 MB)
    u16* xb   = (u16*)d_ws;             // [B*L][256] bf16
    u16* wb   = xb + 2097152;           // Wq|Wk|Wv|Wo bf16, 65536 each
    u16* qr   = wb + 262144;            // [B][H][L][32] bf16
    u16* kr   = qr + 2097152;
    u16* vr   = kr + 2097152;
    u16* attn = vr + 2097152;           // [B*L][256] bf16

    cvt_kernel<<<1152, 256, 0, stream>>>(x, Wq, Wk, Wv, Wo, xb, wb);
    gemm_bt_kernel<<<dim3(4, 128, 3), 256, 0, stream>>>(xb, wb, qr, kr, vr, nullptr, 0);
    attn_kernel<<<dim3(16, 8, 8), 256, 0, stream>>>(qr, kr, vr, lng, lnb, attn);
    gemm_bt_kernel<<<dim3(4, 128, 1), 256, 0, stream>>>(attn, wb + 3 * 65536, nullptr, nullptr, nullptr, outp, 3);
}

// Round 4
// 114.817 us; speedup vs baseline: 1.2007x; 1.1229x over previous
//
#include <hip/hip_runtime.h>
#include <math.h>

typedef unsigned short u16;
typedef unsigned int u32;
typedef __bf16 bf16x8 __attribute__((ext_vector_type(8)));
typedef float f32x4 __attribute__((ext_vector_type(4)));

#define SCALING 0.17677669529663687f   // 32^-0.5
#define LOG2E 1.44269504088896f
#define LOG2_10000 13.287712379549449f

__device__ __forceinline__ u16 f2bf(float f) {
    u32 u; __builtin_memcpy(&u, &f, 4);
    u = u + 0x7FFFu + ((u >> 16) & 1u);
    return (u16)(u >> 16);
}
__device__ __forceinline__ u32 fbits(float f) {
    u32 u; __builtin_memcpy(&u, &f, 4); return u;
}
// pack two f32 -> (bf16(lo) | bf16(hi)<<16), round-half-up via +0x8000
__device__ __forceinline__ u32 pack_bf16(float lo, float hi) {
    return __builtin_amdgcn_perm(fbits(hi) + 0x8000u, fbits(lo) + 0x8000u, 0x07060302u);
}
__device__ __forceinline__ f32x4 mfma16(bf16x8 a, bf16x8 b, f32x4 c) {
    return __builtin_amdgcn_mfma_f32_16x16x32_bf16(a, b, c, 0, 0, 0);
}
__device__ __forceinline__ float decay_l2(int h) {
    // log(1 - 2^(-2 - 5h/8)) * log2(e)  (so exp2(dec*d) == exp(decay*d))
    return logf(1.0f - exp2f(-2.0f - 0.625f * (float)h)) * LOG2E;
}

// ---------------- f32 -> bf16 pre-convert: x (1024 blocks) + 4 weights (32 each)
__global__ __launch_bounds__(256) void cvt_kernel(
    const float* __restrict__ x,
    const float* __restrict__ Wq, const float* __restrict__ Wk,
    const float* __restrict__ Wv, const float* __restrict__ Wo,
    u16* __restrict__ xb, u16* __restrict__ wb) {
    int bid = blockIdx.x;
    const float* src; u16* dst; int off;
    if (bid < 1024) { src = x; dst = xb; off = bid * 2048; }
    else {
        int wsel = (bid - 1024) >> 5;
        src = (wsel == 0) ? Wq : (wsel == 1) ? Wk : (wsel == 2) ? Wv : Wo;
        dst = wb + wsel * 65536;
        off = ((bid - 1024) & 31) * 2048;
    }
    int i = off + threadIdx.x * 8;
    float4 a = *(const float4*)&src[i];
    float4 b = *(const float4*)&src[i + 4];
    union { int4 v; u16 s[8]; } t;
    t.s[0] = f2bf(a.x); t.s[1] = f2bf(a.y); t.s[2] = f2bf(a.z); t.s[3] = f2bf(a.w);
    t.s[4] = f2bf(b.x); t.s[5] = f2bf(b.y); t.s[6] = f2bf(b.z); t.s[7] = f2bf(b.w);
    *(int4*)&dst[i] = t.v;
}

// ---------------- GEMM C[i][e] = sum_j A[i][j] W[e][j]  (all bf16 in) ---------
// modes: 0=q (theta-shift, qkv layout), 1=k (scale+shift), 2=v, 3=plain f32 out
__global__ __launch_bounds__(256) void gemm_bt_kernel(
    const u16* __restrict__ A, const u16* __restrict__ Wb,
    u16* __restrict__ O0, u16* __restrict__ O1, u16* __restrict__ O2,
    float* __restrict__ Of, int mode_base) {
    __shared__ __align__(16) u16 As[64 * 136];
    __shared__ __align__(16) u16 Ws[64 * 136];
    int z = blockIdx.z;
    const u16* W = Wb + z * 65536;
    u16* O = (z == 0) ? O0 : (z == 1) ? O1 : O2;
    int mode = mode_base + z;
    int n0 = blockIdx.x * 64, r0 = blockIdx.y * 64;   // n fast => A row-block L2 reuse
    int tid = threadIdx.x;
    int w = tid >> 6, lane = tid & 63, ln = lane & 15, quad = lane >> 4;
    f32x4 acc[4] = {};
#pragma unroll
    for (int ch = 0; ch < 2; ch++) {
        int k0 = ch * 128;
        if (ch) __syncthreads();
#pragma unroll
        for (int i = 0; i < 4; i++) {
            int c = tid + i * 256;
            int row = c >> 4, seg = c & 15;
            *(int4*)&As[row * 136 + seg * 8] = *(const int4*)&A[(long)(r0 + row) * 256 + k0 + seg * 8];
            *(int4*)&Ws[row * 136 + seg * 8] = *(const int4*)&W[(long)(n0 + row) * 256 + k0 + seg * 8];
        }
        __syncthreads();
#pragma unroll
        for (int kt = 0; kt < 4; kt++) {
            bf16x8 a = *(const bf16x8*)&As[(w * 16 + ln) * 136 + kt * 32 + quad * 8];
#pragma unroll
            for (int nt = 0; nt < 4; nt++) {
                bf16x8 b = *(const bf16x8*)&Ws[(nt * 16 + ln) * 136 + kt * 32 + quad * 8];
                acc[nt] = mfma16(a, b, acc[nt]);
            }
        }
    }
    int rowg = r0 + w * 16 + quad * 4;   // C row = quad*4 + reg
    if (mode == 3) {
#pragma unroll
        for (int nt = 0; nt < 4; nt++) {
            int e = n0 + nt * 16 + ln;
#pragma unroll
            for (int r = 0; r < 4; r++)
                Of[(long)(rowg + r) * 256 + e] = acc[nt][r];
        }
        return;
    }
    float scl = (mode == 1) ? SCALING : 1.0f;
#pragma unroll
    for (int nt = 0; nt < 4; nt++) {
        int e = n0 + nt * 16 + ln;
        int d = e & 31, hh = e >> 5;
        float ang = exp2f(-LOG2_10000 * (1.0f / 15.0f) * (float)(d >> 1));
#pragma unroll
        for (int r = 0; r < 4; r++) {
            int gi = rowg + r;
            int b = gi >> 10, l = gi & 1023;
            float v = acc[nt][r] * scl;
            float p = __shfl_xor(v, 1);   // partner col e^1, same row (uniform exec)
            float res;
            if (mode == 2) {
                res = v;
            } else {
                float idx = (float)((l >> 5) + (l & 31));
                float sv, cv;
                __sincosf(idx * ang, &sv, &cv);
                res = (d & 1) ? (v * cv + p * sv) : (v * cv - p * sv);
            }
            O[(((long)(b * 8 + hh)) * 1024 + l) * 32 + d] = f2bf(res);
        }
    }
}

// ---------------- fused retention + LN + GELU (S^T scheme, factorized mask) ---
__global__ __launch_bounds__(256) void attn_kernel(
    const u16* __restrict__ qr, const u16* __restrict__ kr, const u16* __restrict__ vr,
    const float* __restrict__ lng, const float* __restrict__ lnb,
    u16* __restrict__ out) {
    __shared__ __align__(16) u16 Qs[64 * 40];
    __shared__ __align__(16) u16 Ks[2][64 * 40];
    __shared__ __align__(16) u32 VtW[2][32 * 36];   // V^T packed dwords [d][kkpair]
    __shared__ __align__(16) u32 PsW[4][16 * 36];   // per-wave P^T [q][kkpair]
    __shared__ float Tt[64];
    __shared__ float Ss[32];
    __shared__ float lngS[32], lnbS[32];
    int b = blockIdx.z, h = blockIdx.y, q0 = blockIdx.x * 64;
    int tid = threadIdx.x, w = tid >> 6, lane = tid & 63, ln = lane & 15, quad = lane >> 4;
    long bh = b * 8 + h;
    const u16* qb = qr + bh * 32768;
    const u16* kb = kr + bh * 32768;
    const u16* vb = vr + bh * 32768;
    float dec = decay_l2(h);
    {   // stage Q
        int row = tid >> 2, seg = tid & 3;
        *(int4*)&Qs[row * 40 + seg * 8] = *(const int4*)&qb[(q0 + row) * 32 + seg * 8];
    }
    if (tid < 63) Tt[tid] = exp2f(dec * (float)tid);
    if (tid >= 64 && tid < 96) { lngS[tid - 64] = lng[tid - 64]; lnbS[tid - 64] = lnb[tid - 64]; }
    // K/V staging geometry
    int krow = tid >> 2, kseg = tid & 3;
    int vp = tid >> 3, vseg = tid & 7;
    // prefetch tile 0
    int4 kreg = *(const int4*)&kb[(long)krow * 32 + kseg * 8];
    int2 v0 = *(const int2*)&vb[(long)(vp * 2) * 32 + vseg * 4];
    int2 v1 = *(const int2*)&vb[(long)(vp * 2 + 1) * 32 + vseg * 4];
    __syncthreads();   // Tt, Qs ready
    if (tid < 32) {
        float s = 0.0f;
#pragma unroll
        for (int b2 = 0; b2 < 32; b2++) s += Tt[abs(tid - b2)];
        Ss[tid] = s;
    }
    // write tile 0 to buf 0
    *(int4*)&Ks[0][krow * 40 + kseg * 8] = kreg;
    VtW[0][(vseg * 4 + 0) * 36 + vp] = __builtin_amdgcn_perm(v1.x, v0.x, 0x05040100u);
    VtW[0][(vseg * 4 + 1) * 36 + vp] = __builtin_amdgcn_perm(v1.x, v0.x, 0x07060302u);
    VtW[0][(vseg * 4 + 2) * 36 + vp] = __builtin_amdgcn_perm(v1.y, v0.y, 0x05040100u);
    VtW[0][(vseg * 4 + 3) * 36 + vp] = __builtin_amdgcn_perm(v1.y, v0.y, 0x07060302u);
    // prefetch tile 1
    kreg = *(const int4*)&kb[(long)(64 + krow) * 32 + kseg * 8];
    v0 = *(const int2*)&vb[(long)(64 + vp * 2) * 32 + vseg * 4];
    v1 = *(const int2*)&vb[(long)(64 + vp * 2 + 1) * 32 + vseg * 4];
    __syncthreads();   // Ss + buf0 ready
    int q = q0 + w * 16 + ln;
    int q1i = q >> 5, q2i = q & 31;
    float rqv = rsqrtf(Ss[q1i] * Ss[q2i]);
    bf16x8 aq = *(const bf16x8*)&Qs[(w * 16 + ln) * 40 + quad * 8];   // Q B-frag (fixed)
    float bt[2][4];
#pragma unroll
    for (int s2 = 0; s2 < 2; s2++)
#pragma unroll
        for (int r = 0; r < 4; r++)
            bt[s2][r] = Tt[abs(q2i - (s2 * 16 + quad * 4 + r))];
    f32x4 accO0 = {}, accO1 = {};
    float den = 0.0f;
    u32* psw = &PsW[w][0];
    for (int kt = 0; kt < 16; kt++) {
        int cur = kt & 1;
        float a0 = Tt[abs(q1i - 2 * kt)] * rqv;
        float a1 = Tt[abs(q1i - 2 * kt - 1)] * rqv;
        const u16* ksb = &Ks[cur][0];
        const u32* vtb = &VtW[cur][0];
#pragma unroll
        for (int nt = 0; nt < 4; nt++) {
            bf16x8 ak = *(const bf16x8*)&ksb[(nt * 16 + ln) * 40 + quad * 8];
            f32x4 s = mfma16(ak, aq, (f32x4){0.f, 0.f, 0.f, 0.f});   // S^T rows kk, col q
            float aa = (nt & 2) ? a1 : a0;
            float p0 = s[0] * aa * bt[nt & 1][0];
            float p1 = s[1] * aa * bt[nt & 1][1];
            float p2 = s[2] * aa * bt[nt & 1][2];
            float p3 = s[3] * aa * bt[nt & 1][3];
            den += fabsf(p0); den += fabsf(p1); den += fabsf(p2); den += fabsf(p3);
            int2 pw;
            pw.x = (int)pack_bf16(p0, p1);
            pw.y = (int)pack_bf16(p2, p3);
            *(int2*)&psw[ln * 36 + nt * 8 + quad * 2] = pw;   // wave-private
        }
#pragma unroll
        for (int c = 0; c < 2; c++) {
            bf16x8 bp  = *(const bf16x8*)&psw[ln * 36 + c * 16 + quad * 4];
            bf16x8 av0 = *(const bf16x8*)&vtb[(ln)      * 36 + c * 16 + quad * 4];
            bf16x8 av1 = *(const bf16x8*)&vtb[(16 + ln) * 36 + c * 16 + quad * 4];
            accO0 = mfma16(av0, bp, accO0);
            accO1 = mfma16(av1, bp, accO1);
        }
        if (kt < 15) {
            int nb = 1 - cur;
            *(int4*)&Ks[nb][krow * 40 + kseg * 8] = kreg;
            VtW[nb][(vseg * 4 + 0) * 36 + vp] = __builtin_amdgcn_perm(v1.x, v0.x, 0x05040100u);
            VtW[nb][(vseg * 4 + 1) * 36 + vp] = __builtin_amdgcn_perm(v1.x, v0.x, 0x07060302u);
            VtW[nb][(vseg * 4 + 2) * 36 + vp] = __builtin_amdgcn_perm(v1.y, v0.y, 0x05040100u);
            VtW[nb][(vseg * 4 + 3) * 36 + vp] = __builtin_amdgcn_perm(v1.y, v0.y, 0x07060302u);
            if (kt < 14) {
                int t2 = (kt + 2) * 64;
                kreg = *(const int4*)&kb[(long)(t2 + krow) * 32 + kseg * 8];
                v0 = *(const int2*)&vb[(long)(t2 + vp * 2) * 32 + vseg * 4];
                v1 = *(const int2*)&vb[(long)(t2 + vp * 2 + 1) * 32 + vseg * 4];
            }
            __syncthreads();
        }
    }
    // den: sum over quads (lanes ln, 16+ln, 32+ln, 48+ln)
    den += __shfl_xor(den, 16);
    den += __shfl_xor(den, 32);
    float id = 1.0f / fminf(fmaxf(den, 1.0f), 50000.0f);
    float o[8];
#pragma unroll
    for (int r = 0; r < 4; r++) { o[r] = accO0[r] * id; o[4 + r] = accO1[r] * id; }
    float s1 = 0.0f, s2 = 0.0f;
#pragma unroll
    for (int i = 0; i < 8; i++) { s1 += o[i]; s2 += o[i] * o[i]; }
    s1 += __shfl_xor(s1, 16); s1 += __shfl_xor(s1, 32);
    s2 += __shfl_xor(s2, 16); s2 += __shfl_xor(s2, 32);
    float mean = s1 * (1.0f / 32.0f);
    float var = s2 * (1.0f / 32.0f) - mean * mean;
    float rstd = rsqrtf(var + 1e-5f);
    float xg[8];
#pragma unroll
    for (int nv = 0; nv < 2; nv++)
#pragma unroll
        for (int r = 0; r < 4; r++) {
            int d = nv * 16 + quad * 4 + r;
            float xv = (o[nv * 4 + r] - mean) * rstd * lngS[d] + lnbS[d];
            xg[nv * 4 + r] = 0.5f * xv * (1.0f + erff(xv * 0.70710678118654752f));
        }
    u16* orow = out + ((long)(b * 1024 + q)) * 256 + h * 32;
    int2 st0, st1;
    st0.x = (int)pack_bf16(xg[0], xg[1]); st0.y = (int)pack_bf16(xg[2], xg[3]);
    st1.x = (int)pack_bf16(xg[4], xg[5]); st1.y = (int)pack_bf16(xg[6], xg[7]);
    *(int2*)&orow[quad * 4] = st0;
    *(int2*)&orow[16 + quad * 4] = st1;
}

extern "C" void kernel_launch(void* const* d_in, const int* in_sizes, int n_in,
                              void* d_out, int out_size, void* d_ws, size_t ws_size,
                              hipStream_t stream) {
    const float* x   = (const float*)d_in[0];
    const float* Wq  = (const float*)d_in[1];
    const float* Wk  = (const float*)d_in[2];
    const float* Wv  = (const float*)d_in[3];
    const float* Wo  = (const float*)d_in[4];
    const float* lng = (const float*)d_in[5];
    const float* lnb = (const float*)d_in[6];
    float* outp = (float*)d_out;

    u16* xb   = (u16*)d_ws;             // [B*L][256] bf16
    u16* wb   = xb + 2097152;           // Wq|Wk|Wv|Wo bf16, 65536 each
    u16* qr   = wb + 262144;            // [B][H][L][32] bf16
    u16* kr   = qr + 2097152;
    u16* vr   = kr + 2097152;
    u16* attn = vr + 2097152;           // [B*L][256] bf16

    cvt_kernel<<<1152, 256, 0, stream>>>(x, Wq, Wk, Wv, Wo, xb, wb);
    gemm_bt_kernel<<<dim3(4, 128, 3), 256, 0, stream>>>(xb, wb, qr, kr, vr, nullptr, 0);
    attn_kernel<<<dim3(16, 8, 8), 256, 0, stream>>>(qr, kr, vr, lng, lnb, attn);
    gemm_bt_kernel<<<dim3(4, 128, 1), 256, 0, stream>>>(attn, wb + 3 * 65536, nullptr, nullptr, nullptr, outp, 3);
}